// Round 3
// baseline (64.450 us; speedup 1.0000x reference)
//
#include <hip/hip_runtime.h>
#include <math.h>

// VariationalQuantumAttention — closed-form 2-qubit reduction, minimal-trig.
//
// Reduction chain (all exact algebra, no approximation):
//  (A) Key register + W_int cancel: CRY(q_i->k_i) never mixes query basis
//      states, CRZ(k_i->q_i) is diagonal, and ||M_x psi_k|| = 1 for every
//      query basis state x. P(q0=0,q1=0) depends only on the query circuit.
//  (B) Layer-2 RZs commute to just before the layer-2 CNOT chain; diagonal
//      phases followed by a permutation + diagonal measurement are
//      unobservable. Drop.
//  (C) Layer-2 CNOT chain: preimage of the measured set {wire0=wire1=0}
//      under CNOT(0,1),(1,2),(2,3) is the same set. Drop.
//  (D) Layer-2 RYs on wires 2,3 act unitarily inside the measured block
//      (summed over wires 2,3). Drop.
//  (E) Trace out wires 2,3: CNOT(2,3) is unitary on the traced pair;
//      CNOT(1,2) with wire 2 in pure state psi2 = dephasing on wire 1 with
//      eta = <psi2|X|psi2> = sin(Theta2)*cos(phi2). Wire 3 vanishes.
//  (F) All RZ angles phi_i = Wqz[0][i] appear only as cos(phi0), cos(phi1),
//      cos(phi0 +/- phi1), cos(phi2) — thread-uniform.
//  (G) NEW: layer-2 RY half-angles differ from layer-1 half-angles by the
//      thread-uniform offset d_i = (Wqy[1][i] - Wqy[0][i])/2, so
//      (A0,-A1) = R(d0)·(c0,s0) and (B0,-B1) = R(d1)·(c1,s1) — plane
//      rotations, no extra sincos. eta needs only full-angle sin(Theta2).
//
// Per-thread data-dependent transcendentals: 3 exp (tanh) + 2 sincos + 1 sin.
//
//   Theta_i = tanh(q_i)*pi + Wqy[0][i]
//   c_i = cos(Theta_i/2), s_i = sin(Theta_i/2)
//   A0 = c0*cos d0 - s0*sin d0,  A1 = -(s0*cos d0 + c0*sin d0)
//   B0 = c1*cos d1 - s1*sin d1,  B1 = -(s1*cos d1 + c1*sin d1)
//   P0 = A0*c0*c1, P1 = A1*s0*s1, Q0 = A0*c0*s1, Q1 = A1*s0*c1
//   eta = sin(Theta2)*cos(phi2)
//   P(00) = B0^2*(P0^2+P1^2+2*P0*P1*cos(phi0+phi1))
//         + B1^2*(Q0^2+Q1^2+2*Q0*Q1*cos(phi0-phi1))
//         + 2*eta*B0*B1*((P0*Q0+P1*Q1)*cos(phi1)+(P0*Q1+P1*Q0)*cos(phi0))

// tanh via exp: tanh(x) = 1 - 2/(e^{2x}+1). v_exp_f32 + v_rcp_f32.
__device__ __forceinline__ float fast_tanh(float x) {
    const float e = __expf(2.0f * x);
    return 1.0f - 2.0f / (e + 1.0f);
}

__global__ __launch_bounds__(64) void vqa_query_kernel(
    const float* __restrict__ query,   // [B][64], only first 3 cols used
    const float* __restrict__ Wqy,     // [2][4]
    const float* __restrict__ Wqz,     // [2][4]
    float* __restrict__ out,           // [B]
    int B)
{
    const int b = blockIdx.x * blockDim.x + threadIdx.x;
    if (b >= B) return;

    // One float4 load per row (12 B used of each 256 B row).
    const float4 qv = *reinterpret_cast<const float4*>(query + (size_t)b * 64);

    const float PI = 3.14159265358979323846f;
    const float q0 = fast_tanh(qv.x) * PI;
    const float q1 = fast_tanh(qv.y) * PI;
    const float q2 = fast_tanh(qv.z) * PI;

    // Thread-uniform weight trig (scalar-operand, wave-uniform results).
    const float C0 = __cosf(Wqz[0]);
    const float C1 = __cosf(Wqz[1]);
    const float Cp = __cosf(Wqz[0] + Wqz[1]);
    const float Cm = __cosf(Wqz[0] - Wqz[1]);
    const float C2 = __cosf(Wqz[2]);
    float cd0, sd0, cd1, sd1;
    __sincosf(0.5f * (Wqy[4] - Wqy[0]), &sd0, &cd0);
    __sincosf(0.5f * (Wqy[5] - Wqy[1]), &sd1, &cd1);

    // Layer-1 RY half-angles (data rotation fused with weight rotation).
    float c0, s0, c1, s1;
    __sincosf(0.5f * (q0 + Wqy[0]), &s0, &c0);
    __sincosf(0.5f * (q1 + Wqy[1]), &s1, &c1);

    // Layer-2 RY coefficients via uniform plane rotation (no sincos).
    const float A0 = c0 * cd0 - s0 * sd0;
    const float A1 = -(s0 * cd0 + c0 * sd0);
    const float B0 = c1 * cd1 - s1 * sd1;
    const float B1 = -(s1 * cd1 + c1 * sd1);

    // Dephasing factor: full-angle sine, single transcendental.
    const float eta = __sinf(q2 + Wqy[2]) * C2;

    const float P0 = A0 * c0 * c1;
    const float P1 = A1 * s0 * s1;
    const float Q0 = A0 * c0 * s1;
    const float Q1 = A1 * s0 * c1;

    const float T0 = P0 * P0 + P1 * P1 + 2.0f * P0 * P1 * Cp;  // |t0|^2
    const float T1 = Q0 * Q0 + Q1 * Q1 + 2.0f * Q0 * Q1 * Cm;  // |t1|^2
    const float X  = (P0 * Q0 + P1 * Q1) * C1
                   + (P0 * Q1 + P1 * Q0) * C0;                 // Re(t0*conj(t1))

    out[b] = B0 * B0 * T0 + B1 * B1 * T1 + 2.0f * eta * B0 * B1 * X;
}

extern "C" void kernel_launch(void* const* d_in, const int* in_sizes, int n_in,
                              void* d_out, int out_size, void* d_ws, size_t ws_size,
                              hipStream_t stream) {
    const float* query = (const float*)d_in[0];
    // d_in[1] = key      (unused — proven irrelevant)
    const float* Wqy   = (const float*)d_in[2];
    const float* Wqz   = (const float*)d_in[3];
    // d_in[4] = W_k_y, d_in[5] = W_k_z, d_in[6] = W_int (all unused)
    float* out = (float*)d_out;

    const int B = in_sizes[0] / 64;   // feature dim D = 64 per reference

    // Latency-bound at this size: one wave per block spreads the 128 waves
    // across 128 CUs instead of packing 4 waves onto each of 32 CUs.
    const int block = 64;
    const int grid = (B + block - 1) / block;
    vqa_query_kernel<<<grid, block, 0, stream>>>(query, Wqy, Wqz, out, B);
}